// Round 6
// baseline (573.493 us; speedup 1.0000x reference)
//
#include <hip/hip_runtime.h>
#include <hip/hip_bf16.h>

// PretrainedCNN: normalized-convolution U-Net, B=16, 512x640, NC=2.
// Inputs fp32 (bf16-rounded values in fp32 storage); OUTPUT d_out is fp32:
// xout plane (n0 elems) then cout plane (n0 elems).
// Intermediates fp32 planar [ch][b][h][w], plane stride NB*npix.
// Workspace: 8*n0 floats (167.8 MB); sub-res buffers overlay FB (dead after L3).

#define NB 16

constexpr int TX = 32, TY = 8;

// ---------------- 5x5 normalized conv, Cout=2 ----------------
template<int CIN>
__global__ __launch_bounds__(256)
void navg5_kernel(const float* __restrict__ xin, const float* __restrict__ cin,
                  const float* __restrict__ w, const float* __restrict__ bias,
                  float* __restrict__ xout, float* __restrict__ cout,
                  int H, int W) {
    __shared__ float sc[CIN][TY + 4][TX + 4];
    __shared__ float sp[CIN][TY + 4][TX + 4];
    __shared__ float sw[2 * CIN * 25];
    __shared__ float sb[2];
    __shared__ float sinv[2];

    const int b = blockIdx.z;
    const int npix = H * W;
    const size_t chs = (size_t)NB * npix;
    const int tid = threadIdx.y * TX + threadIdx.x;

    for (int i = tid; i < 2 * CIN * 25; i += 256) sw[i] = w[i];
    __syncthreads();   // sw complete before the sum below
    if (tid < 2) {
        float s = 0.f;
        for (int i = 0; i < CIN * 25; ++i) s += sw[tid * CIN * 25 + i];
        sinv[tid] = 1.f / s;
        sb[tid] = bias[tid];
    }

    const int y0 = blockIdx.y * TY - 2;
    const int x0 = blockIdx.x * TX - 2;
    for (int ci = 0; ci < CIN; ++ci) {
        const size_t base = (size_t)ci * chs + (size_t)b * npix;
        for (int i = tid; i < (TY + 4) * (TX + 4); i += 256) {
            const int ly = i / (TX + 4), lx = i % (TX + 4);
            const int gy = y0 + ly, gx = x0 + lx;
            float cv = 0.f, pv = 0.f;
            if (gy >= 0 && gy < H && gx >= 0 && gx < W) {
                const size_t o = base + (size_t)gy * W + gx;
                cv = cin[o];
                pv = xin[o] * cv;
            }
            sc[ci][ly][lx] = cv;
            sp[ci][ly][lx] = pv;
        }
    }
    __syncthreads();

    const int gh = blockIdx.y * TY + threadIdx.y;
    const int gw = blockIdx.x * TX + threadIdx.x;
    if (gh < H && gw < W) {
        const size_t off = (size_t)b * npix + (size_t)gh * W + gw;
#pragma unroll
        for (int o = 0; o < 2; ++o) {
            float ca = 0.f, pa = 0.f;
#pragma unroll
            for (int ci = 0; ci < CIN; ++ci)
#pragma unroll
                for (int kh = 0; kh < 5; ++kh)
#pragma unroll
                    for (int kw = 0; kw < 5; ++kw) {
                        const float wv = sw[((o * CIN + ci) * 5 + kh) * 5 + kw];
                        ca += wv * sc[ci][threadIdx.y + kh][threadIdx.x + kw];
                        pa += wv * sp[ci][threadIdx.y + kh][threadIdx.x + kw];
                    }
            xout[(size_t)o * chs + off] = pa / (ca + 1e-20f) + sb[o];
            cout[(size_t)o * chs + off] = ca * sinv[o];
        }
    }
}

// ---------------- 2x2 argmax-of-c pool (first-wins like jnp.argmax) ----------------
__global__ void pool_kernel(const float* __restrict__ xin, const float* __restrict__ cin,
                            float* __restrict__ xout, float* __restrict__ cout,
                            int Hh, int Wh) {
    const int nplane = Hh * Wh;
    const int total = 2 * NB * nplane;
    const int idx = blockIdx.x * blockDim.x + threadIdx.x;
    if (idx >= total) return;
    const int p = idx / nplane;             // plane over [ch][b]
    const int q = idx - p * nplane;
    const int h = q / Wh, wc = q - h * Wh;
    const int Wf = 2 * Wh;
    const size_t ibase = (size_t)p * 4 * nplane + (size_t)(2 * h) * Wf + 2 * wc;
    const float c00 = cin[ibase], c01 = cin[ibase + 1];
    const float c10 = cin[ibase + Wf], c11 = cin[ibase + Wf + 1];
    float best = c00; size_t boff = ibase;
    if (c01 > best) { best = c01; boff = ibase + 1; }
    if (c10 > best) { best = c10; boff = ibase + Wf; }
    if (c11 > best) { best = c11; boff = ibase + Wf + 1; }
    cout[idx] = best * 0.25f;
    xout[idx] = xin[boff];
}

// ---------------- 3x3 navg over virtual concat [A(2ch) ; B(2ch)] ----------------
// UPA/UPB: that source is at (H/2, W/2), nearest-upsampled 2x on the fly.
// FUSE: additionally apply the final 1x1 navg (w4, b4); outputs go to xout/cout
// planes (fp32) — for FUSE these are the d_out planes.
template<bool UPA, bool UPB, bool FUSE>
__global__ __launch_bounds__(256)
void navg3_kernel(const float* __restrict__ xA, const float* __restrict__ cA,
                  const float* __restrict__ xB, const float* __restrict__ cB,
                  const float* __restrict__ w, const float* __restrict__ bias,
                  const float* __restrict__ w4, const float* __restrict__ b4,
                  float* __restrict__ xout, float* __restrict__ cout,
                  int H, int W) {
    __shared__ float sc[4][TY + 2][TX + 2];
    __shared__ float sp[4][TY + 2][TX + 2];
    __shared__ float sw[72];
    __shared__ float sb[2];
    __shared__ float sinv[2];

    const int b = blockIdx.z;
    const int npix = H * W;
    const size_t chs = (size_t)NB * npix;
    const int tid = threadIdx.y * TX + threadIdx.x;

    if (tid < 72) sw[tid] = w[tid];
    __syncthreads();
    if (tid < 2) {
        float s = 0.f;
        for (int i = 0; i < 36; ++i) s += sw[tid * 36 + i];
        sinv[tid] = 1.f / s;
        sb[tid] = bias[tid];
    }

    const int y0 = blockIdx.y * TY - 1;
    const int x0 = blockIdx.x * TX - 1;
    const int Ws2 = W >> 1;
    const int npixS = (H >> 1) * Ws2;

#pragma unroll
    for (int ch = 0; ch < 4; ++ch) {
        const bool up = (ch < 2) ? UPA : UPB;
        const float* xs = (ch < 2) ? xA : xB;
        const float* cs = (ch < 2) ? cA : cB;
        const int sch = ch & 1;
        const size_t base = up ? ((size_t)sch * NB * npixS + (size_t)b * npixS)
                               : ((size_t)sch * chs + (size_t)b * npix);
        for (int i = tid; i < (TY + 2) * (TX + 2); i += 256) {
            const int ly = i / (TX + 2), lx = i % (TX + 2);
            const int gy = y0 + ly, gx = x0 + lx;
            float cv = 0.f, pv = 0.f;
            if (gy >= 0 && gy < H && gx >= 0 && gx < W) {
                const size_t o = up ? (base + (size_t)(gy >> 1) * Ws2 + (gx >> 1))
                                    : (base + (size_t)gy * W + gx);
                cv = cs[o];
                pv = xs[o] * cv;
            }
            sc[ch][ly][lx] = cv;
            sp[ch][ly][lx] = pv;
        }
    }
    __syncthreads();

    const int gh = blockIdx.y * TY + threadIdx.y;
    const int gw = blockIdx.x * TX + threadIdx.x;
    if (gh < H && gw < W) {
        const size_t off = (size_t)b * npix + (size_t)gh * W + gw;
        float xv[2], cv[2];
#pragma unroll
        for (int o = 0; o < 2; ++o) {
            float ca = 0.f, pa = 0.f;
#pragma unroll
            for (int ci = 0; ci < 4; ++ci)
#pragma unroll
                for (int kh = 0; kh < 3; ++kh)
#pragma unroll
                    for (int kw = 0; kw < 3; ++kw) {
                        const float wv = sw[((o * 4 + ci) * 3 + kh) * 3 + kw];
                        ca += wv * sc[ci][threadIdx.y + kh][threadIdx.x + kw];
                        pa += wv * sp[ci][threadIdx.y + kh][threadIdx.x + kw];
                    }
            xv[o] = pa / (ca + 1e-20f) + sb[o];
            cv[o] = ca * sinv[o];
        }
        if (FUSE) {
            const float w40 = w4[0], w41 = w4[1];
            const float ca4 = w40 * cv[0] + w41 * cv[1];
            const float xo = (w40 * xv[0] * cv[0] + w41 * xv[1] * cv[1]) / (ca4 + 1e-20f) + b4[0];
            const float co = ca4 / (w40 + w41);
            xout[off] = xo;           // fp32 d_out plane 0 (xout)
            cout[off] = co;           // fp32 d_out plane 1 (cout)
        } else {
            xout[off] = xv[0]; xout[chs + off] = xv[1];
            cout[off] = cv[0]; cout[chs + off] = cv[1];
        }
    }
}

extern "C" void kernel_launch(void* const* d_in, const int* in_sizes, int n_in,
                              void* d_out, int out_size, void* d_ws, size_t ws_size,
                              hipStream_t stream) {
    const float* x0  = (const float*)d_in[0];
    const float* c0  = (const float*)d_in[1];
    const float* w1  = (const float*)d_in[2];
    const float* w2  = (const float*)d_in[3];
    const float* w3  = (const float*)d_in[4];
    const float* w4  = (const float*)d_in[5];
    const float* w34 = (const float*)d_in[6];
    const float* w23 = (const float*)d_in[7];
    const float* w12 = (const float*)d_in[8];
    const float* b1  = (const float*)d_in[9];
    const float* b2  = (const float*)d_in[10];
    const float* b3  = (const float*)d_in[11];
    const float* b4  = (const float*)d_in[12];
    const float* b34 = (const float*)d_in[13];
    const float* b23 = (const float*)d_in[14];
    const float* b12 = (const float*)d_in[15];

    float* out = (float*)d_out;   // fp32: xout plane then cout plane

    const int H0 = 512, W0 = 640, H1 = 256, W1 = 320, H2 = 128, W2 = 160, H3 = 64, W3 = 80;
    const size_t n0 = (size_t)NB * H0 * W0;   // 5,242,880
    const size_t n1 = n0 / 4, n2 = n0 / 16, n3 = n0 / 64;

    // ---- workspace layout: 8*n0 floats (167.8 MB) ----
    float* ws = (float*)d_ws;
    float* FAx = ws;            // x1 (2ch) -- persists to the end
    float* FAc = ws + 2 * n0;   // c1 (2ch)
    float* FB  = ws + 4 * n0;   // full-res ping buffer; sub-res overlay after L3
    float* FBx = FB;
    float* FBc = FB + 2 * n0;

    float* sub = FB;            // overlay (FB dead after L3); total 2.625*n0 <= 4*n0
    float* HPx = sub;               sub += 2 * n1;
    float* HPc = sub;               sub += 2 * n1;
    float* HAx = sub;               sub += 2 * n1;
    float* HAc = sub;               sub += 2 * n1;
    float* QPx = sub;               sub += 2 * n2;
    float* QPc = sub;               sub += 2 * n2;
    float* QAx = sub;               sub += 2 * n2;
    float* QAc = sub;               sub += 2 * n2;
    float* EPx = sub;               sub += 2 * n3;
    float* EPc = sub;               sub += 2 * n3;
    float* EAx = sub;               sub += 2 * n3;
    float* EAc = sub;               sub += 2 * n3;

    dim3 blk(TX, TY);
    auto gdim = [](int W, int H) { return dim3((W + TX - 1) / TX, (H + TY - 1) / TY, NB); };

    // L1..L3 full res: -> FA -> FB -> FA  (x1,c1 end in FA)
    navg5_kernel<1><<<gdim(W0, H0), blk, 0, stream>>>(x0, c0, w1, b1, FAx, FAc, H0, W0);
    navg5_kernel<2><<<gdim(W0, H0), blk, 0, stream>>>(FAx, FAc, w2, b2, FBx, FBc, H0, W0);
    navg5_kernel<2><<<gdim(W0, H0), blk, 0, stream>>>(FBx, FBc, w3, b3, FAx, FAc, H0, W0);

    // pool -> half (HP overlays FB region; full-res FB data dead now)
    pool_kernel<<<(int)((2 * n1 + 255) / 256), 256, 0, stream>>>(FAx, FAc, HPx, HPc, H1, W1);
    // L5: HP -> HA (w2,b2)
    navg5_kernel<2><<<gdim(W1, H1), blk, 0, stream>>>(HPx, HPc, w2, b2, HAx, HAc, H1, W1);
    // L6: HA -> HP (w3,b3)   [HP := x2_ds,c2_ds]
    navg5_kernel<2><<<gdim(W1, H1), blk, 0, stream>>>(HAx, HAc, w3, b3, HPx, HPc, H1, W1);
    // pool -> quarter
    pool_kernel<<<(int)((2 * n2 + 255) / 256), 256, 0, stream>>>(HPx, HPc, QPx, QPc, H2, W2);
    // L8: QP -> QA (w2,b2)   [QA := x3_ds,c3_ds]
    navg5_kernel<2><<<gdim(W2, H2), blk, 0, stream>>>(QPx, QPc, w2, b2, QAx, QAc, H2, W2);
    // pool -> eighth
    pool_kernel<<<(int)((2 * n3 + 255) / 256), 256, 0, stream>>>(QAx, QAc, EPx, EPc, H3, W3);
    // L10: EP -> EA (w2,b2)  [EA := x4_ds,c4_ds]
    navg5_kernel<2><<<gdim(W3, H3), blk, 0, stream>>>(EPx, EPc, w2, b2, EAx, EAc, H3, W3);
    // L12: cat(QA, up2(EA)) -> QP (w34,b34)
    navg3_kernel<false, true, false><<<gdim(W2, H2), blk, 0, stream>>>(
        QAx, QAc, EAx, EAc, w34, b34, nullptr, nullptr, QPx, QPc, H2, W2);
    // L14: cat(HP, up2(QP)) -> HA (w23,b23)
    navg3_kernel<false, true, false><<<gdim(W1, H1), blk, 0, stream>>>(
        HPx, HPc, QPx, QPc, w23, b23, nullptr, nullptr, HAx, HAc, H1, W1);
    // L16 + L17 fused: cat(up2(HA), FA) -> full res, then 1x1 w4, fp32 out
    navg3_kernel<true, false, true><<<gdim(W0, H0), blk, 0, stream>>>(
        HAx, HAc, FAx, FAc, w12, b12, w4, b4, out, out + n0, H0, W0);
}

// Round 7
// 512.526 us; speedup vs baseline: 1.1190x; 1.1190x over previous
//
#include <hip/hip_runtime.h>

// PretrainedCNN: normalized-convolution U-Net, B=16, 512x640, NC=2.
// Inputs fp32; OUTPUT d_out fp32: xout plane (n0) then cout plane (n0).
// Intermediates fp32 planar [ch][b][h][w], plane stride NB*npix.
// Round 7: fused encoder full-res kernel (L1+L2+L3+pool) — cuts ~800MB HBM
// traffic of the full-res encoder to ~150MB. 4px/thread register blocking,
// float4 LDS reads, weights via uniform (SGPR-cached) global reads.

#define NB 16

constexpr int TX = 32, TY = 8;

// ================= fused full-res encoder =================
// output tile 32x16; stage 44x28 (halo 6); L1 40x24 (halo 4); L2 36x20 (halo 2)
constexpr int FTW = 32, FTH = 16;
constexpr int FSW = 44, FSH = 28;
constexpr int FAW = 40, FAH = 24;
constexpr int FBW = 36, FBH = 20;

template<int CIN>
__device__ __forceinline__ void conv5x4(const float* sc, const float* sp,
                                        int chStride, int rw,
                                        const float* __restrict__ w,
                                        float ca[2][4], float pa[2][4]) {
#pragma unroll
    for (int o = 0; o < 2; ++o)
#pragma unroll
        for (int j = 0; j < 4; ++j) { ca[o][j] = 0.f; pa[o][j] = 0.f; }
#pragma unroll
    for (int ci = 0; ci < CIN; ++ci) {
#pragma unroll
        for (int kh = 0; kh < 5; ++kh) {
            const float* rc = sc + ci * chStride + kh * rw;
            const float* rp = sp + ci * chStride + kh * rw;
            float cw[8], pw[8];
            *(float4*)&cw[0] = *(const float4*)rc;
            *(float4*)&cw[4] = *(const float4*)(rc + 4);
            *(float4*)&pw[0] = *(const float4*)rp;
            *(float4*)&pw[4] = *(const float4*)(rp + 4);
#pragma unroll
            for (int kw = 0; kw < 5; ++kw) {
                const float w0 = w[(0 * CIN + ci) * 25 + kh * 5 + kw];
                const float w1 = w[(1 * CIN + ci) * 25 + kh * 5 + kw];
#pragma unroll
                for (int j = 0; j < 4; ++j) {
                    ca[0][j] += w0 * cw[j + kw]; pa[0][j] += w0 * pw[j + kw];
                    ca[1][j] += w1 * cw[j + kw]; pa[1][j] += w1 * pw[j + kw];
                }
            }
        }
    }
}

__global__ __launch_bounds__(256)
void enc_full_kernel(const float* __restrict__ x0, const float* __restrict__ c0,
                     const float* __restrict__ w1, const float* __restrict__ b1,
                     const float* __restrict__ w2, const float* __restrict__ b2,
                     const float* __restrict__ w3, const float* __restrict__ b3,
                     float* __restrict__ FAx, float* __restrict__ FAc,
                     float* __restrict__ HPx, float* __restrict__ HPc,
                     int H, int W) {
    __shared__ __align__(16) float s0c[FSH][FSW], s0p[FSH][FSW];
    __shared__ __align__(16) float s1c[2][FAH][FAW], s1p[2][FAH][FAW];
    __shared__ __align__(16) float s2c[2][FBH][FBW], s2p[2][FBH][FBW];

    const int tid = threadIdx.x;
    const int b = blockIdx.z;
    const int Y0 = blockIdx.y * FTH, X0 = blockIdx.x * FTW;
    const int npix = H * W;
    const size_t bofs = (size_t)b * npix;
    const size_t chs = (size_t)NB * npix;

    // uniform scalar sums (SALU): 1/sum(w) and biases per layer/channel
    auto wsum = [](const float* w, int n) { float s = 0.f; for (int i = 0; i < n; ++i) s += w[i]; return s; };
    const float inv1[2] = {1.f / wsum(w1, 25),  1.f / wsum(w1 + 25, 25)};
    const float inv2[2] = {1.f / wsum(w2, 50),  1.f / wsum(w2 + 50, 50)};
    const float inv3[2] = {1.f / wsum(w3, 50),  1.f / wsum(w3 + 50, 50)};
    const float bb1[2] = {b1[0], b1[1]};
    const float bb2[2] = {b2[0], b2[1]};
    const float bb3[2] = {b3[0], b3[1]};

    // stage input tile (zero-padded outside image)
    for (int i = tid; i < FSH * FSW; i += 256) {
        const int ly = i / FSW, lx = i - ly * FSW;
        const int gy = Y0 + ly - 6, gx = X0 + lx - 6;
        float cv = 0.f, pv = 0.f;
        if (gy >= 0 && gy < H && gx >= 0 && gx < W) {
            const size_t o = bofs + (size_t)gy * W + gx;
            cv = c0[o]; pv = x0[o] * cv;
        }
        s0c[ly][lx] = cv; s0p[ly][lx] = pv;
    }
    __syncthreads();

    // ---- L1: 40x24, CIN=1 ----
    if (tid < FAH * (FAW / 4)) {
        const int row = tid / (FAW / 4), lx = (tid % (FAW / 4)) * 4;
        float ca[2][4], pa[2][4];
        conv5x4<1>(&s0c[row][lx], &s0p[row][lx], 0, FSW, w1, ca, pa);
        const int gy = Y0 + row - 4;
#pragma unroll
        for (int j = 0; j < 4; ++j) {
            const int gx = X0 + lx + j - 4;
            const bool in = (gy >= 0 && gy < H && gx >= 0 && gx < W);
#pragma unroll
            for (int o = 0; o < 2; ++o) {
                float cv = in ? ca[o][j] * inv1[o] : 0.f;
                float xv = pa[o][j] / (ca[o][j] + 1e-20f) + bb1[o];
                s1c[o][row][lx + j] = cv;
                s1p[o][row][lx + j] = in ? xv * cv : 0.f;
            }
        }
    }
    __syncthreads();

    // ---- L2: 36x20, CIN=2 ----
    if (tid < FBH * (FBW / 4)) {
        const int row = tid / (FBW / 4), lx = (tid % (FBW / 4)) * 4;
        float ca[2][4], pa[2][4];
        conv5x4<2>(&s1c[0][row][lx], &s1p[0][row][lx], FAH * FAW, FAW, w2, ca, pa);
        const int gy = Y0 + row - 2;
#pragma unroll
        for (int j = 0; j < 4; ++j) {
            const int gx = X0 + lx + j - 2;
            const bool in = (gy >= 0 && gy < H && gx >= 0 && gx < W);
#pragma unroll
            for (int o = 0; o < 2; ++o) {
                float cv = in ? ca[o][j] * inv2[o] : 0.f;
                float xv = pa[o][j] / (ca[o][j] + 1e-20f) + bb2[o];
                s2c[o][row][lx + j] = cv;
                s2p[o][row][lx + j] = in ? xv * cv : 0.f;
            }
        }
    }
    __syncthreads();

    // ---- L3: 32x16, CIN=2 -> global FA + pooled HP ----
    if (tid < FTH * (FTW / 4)) {
        const int row = tid / (FTW / 4), lx = (tid % (FTW / 4)) * 4;
        float ca[2][4], pa[2][4];
        conv5x4<2>(&s2c[0][row][lx], &s2p[0][row][lx], FBH * FBW, FBW, w3, ca, pa);
        float xv[2][4], cv[2][4];
#pragma unroll
        for (int o = 0; o < 2; ++o)
#pragma unroll
            for (int j = 0; j < 4; ++j) {
                xv[o][j] = pa[o][j] / (ca[o][j] + 1e-20f) + bb3[o];
                cv[o][j] = ca[o][j] * inv3[o];
            }
        const int gy = Y0 + row;
        const size_t base = bofs + (size_t)gy * W + (X0 + lx);
#pragma unroll
        for (int o = 0; o < 2; ++o) {
            *(float4*)(FAx + o * chs + base) = make_float4(xv[o][0], xv[o][1], xv[o][2], xv[o][3]);
            *(float4*)(FAc + o * chs + base) = make_float4(cv[o][0], cv[o][1], cv[o][2], cv[o][3]);
        }
        // pool 2x2 (first-wins argmax of c): partner row via shfl_xor(8) — row pairs share a wave
        float pcv[2][4], pxv[2][4];
#pragma unroll
        for (int o = 0; o < 2; ++o)
#pragma unroll
            for (int j = 0; j < 4; ++j) {
                pcv[o][j] = __shfl_xor(cv[o][j], 8);
                pxv[o][j] = __shfl_xor(xv[o][j], 8);
            }
        if ((row & 1) == 0) {
            const int Wh = W >> 1;
            const int np1 = (H >> 1) * Wh;
            const int hy = (Y0 + row) >> 1;
            const int hx0 = (X0 + lx) >> 1;
#pragma unroll
            for (int o = 0; o < 2; ++o)
#pragma unroll
                for (int g = 0; g < 2; ++g) {
                    const float c00 = cv[o][2 * g], c01 = cv[o][2 * g + 1];
                    const float c10 = pcv[o][2 * g], c11 = pcv[o][2 * g + 1];
                    const float x00 = xv[o][2 * g], x01 = xv[o][2 * g + 1];
                    const float x10 = pxv[o][2 * g], x11 = pxv[o][2 * g + 1];
                    float bc = c00, bx = x00;
                    if (c01 > bc) { bc = c01; bx = x01; }
                    if (c10 > bc) { bc = c10; bx = x10; }
                    if (c11 > bc) { bc = c11; bx = x11; }
                    const size_t ho = (size_t)o * NB * np1 + (size_t)b * np1 + (size_t)hy * Wh + hx0 + g;
                    HPc[ho] = bc * 0.25f;
                    HPx[ho] = bx;
                }
        }
    }
}

// ================= original (validated) kernels for sub-res =================
template<int CIN>
__global__ __launch_bounds__(256)
void navg5_kernel(const float* __restrict__ xin, const float* __restrict__ cin,
                  const float* __restrict__ w, const float* __restrict__ bias,
                  float* __restrict__ xout, float* __restrict__ cout,
                  int H, int W) {
    __shared__ float sc[CIN][TY + 4][TX + 4];
    __shared__ float sp[CIN][TY + 4][TX + 4];
    __shared__ float sw[2 * CIN * 25];
    __shared__ float sb[2];
    __shared__ float sinv[2];

    const int b = blockIdx.z;
    const int npix = H * W;
    const size_t chs = (size_t)NB * npix;
    const int tid = threadIdx.y * TX + threadIdx.x;

    for (int i = tid; i < 2 * CIN * 25; i += 256) sw[i] = w[i];
    __syncthreads();
    if (tid < 2) {
        float s = 0.f;
        for (int i = 0; i < CIN * 25; ++i) s += sw[tid * CIN * 25 + i];
        sinv[tid] = 1.f / s;
        sb[tid] = bias[tid];
    }

    const int y0 = blockIdx.y * TY - 2;
    const int x0 = blockIdx.x * TX - 2;
    for (int ci = 0; ci < CIN; ++ci) {
        const size_t base = (size_t)ci * chs + (size_t)b * npix;
        for (int i = tid; i < (TY + 4) * (TX + 4); i += 256) {
            const int ly = i / (TX + 4), lx = i % (TX + 4);
            const int gy = y0 + ly, gx = x0 + lx;
            float cv = 0.f, pv = 0.f;
            if (gy >= 0 && gy < H && gx >= 0 && gx < W) {
                const size_t o = base + (size_t)gy * W + gx;
                cv = cin[o];
                pv = xin[o] * cv;
            }
            sc[ci][ly][lx] = cv;
            sp[ci][ly][lx] = pv;
        }
    }
    __syncthreads();

    const int gh = blockIdx.y * TY + threadIdx.y;
    const int gw = blockIdx.x * TX + threadIdx.x;
    if (gh < H && gw < W) {
        const size_t off = (size_t)b * npix + (size_t)gh * W + gw;
#pragma unroll
        for (int o = 0; o < 2; ++o) {
            float ca = 0.f, pa = 0.f;
#pragma unroll
            for (int ci = 0; ci < CIN; ++ci)
#pragma unroll
                for (int kh = 0; kh < 5; ++kh)
#pragma unroll
                    for (int kw = 0; kw < 5; ++kw) {
                        const float wv = sw[((o * CIN + ci) * 5 + kh) * 5 + kw];
                        ca += wv * sc[ci][threadIdx.y + kh][threadIdx.x + kw];
                        pa += wv * sp[ci][threadIdx.y + kh][threadIdx.x + kw];
                    }
            xout[(size_t)o * chs + off] = pa / (ca + 1e-20f) + sb[o];
            cout[(size_t)o * chs + off] = ca * sinv[o];
        }
    }
}

__global__ void pool_kernel(const float* __restrict__ xin, const float* __restrict__ cin,
                            float* __restrict__ xout, float* __restrict__ cout,
                            int Hh, int Wh) {
    const int nplane = Hh * Wh;
    const int total = 2 * NB * nplane;
    const int idx = blockIdx.x * blockDim.x + threadIdx.x;
    if (idx >= total) return;
    const int p = idx / nplane;
    const int q = idx - p * nplane;
    const int h = q / Wh, wc = q - h * Wh;
    const int Wf = 2 * Wh;
    const size_t ibase = (size_t)p * 4 * nplane + (size_t)(2 * h) * Wf + 2 * wc;
    const float c00 = cin[ibase], c01 = cin[ibase + 1];
    const float c10 = cin[ibase + Wf], c11 = cin[ibase + Wf + 1];
    float best = c00; size_t boff = ibase;
    if (c01 > best) { best = c01; boff = ibase + 1; }
    if (c10 > best) { best = c10; boff = ibase + Wf; }
    if (c11 > best) { best = c11; boff = ibase + Wf + 1; }
    cout[idx] = best * 0.25f;
    xout[idx] = xin[boff];
}

template<bool UPA, bool UPB, bool FUSE>
__global__ __launch_bounds__(256)
void navg3_kernel(const float* __restrict__ xA, const float* __restrict__ cA,
                  const float* __restrict__ xB, const float* __restrict__ cB,
                  const float* __restrict__ w, const float* __restrict__ bias,
                  const float* __restrict__ w4, const float* __restrict__ b4,
                  float* __restrict__ xout, float* __restrict__ cout,
                  int H, int W) {
    __shared__ float sc[4][TY + 2][TX + 2];
    __shared__ float sp[4][TY + 2][TX + 2];
    __shared__ float sw[72];
    __shared__ float sb[2];
    __shared__ float sinv[2];

    const int b = blockIdx.z;
    const int npix = H * W;
    const size_t chs = (size_t)NB * npix;
    const int tid = threadIdx.y * TX + threadIdx.x;

    if (tid < 72) sw[tid] = w[tid];
    __syncthreads();
    if (tid < 2) {
        float s = 0.f;
        for (int i = 0; i < 36; ++i) s += sw[tid * 36 + i];
        sinv[tid] = 1.f / s;
        sb[tid] = bias[tid];
    }

    const int y0 = blockIdx.y * TY - 1;
    const int x0 = blockIdx.x * TX - 1;
    const int Ws2 = W >> 1;
    const int npixS = (H >> 1) * Ws2;

#pragma unroll
    for (int ch = 0; ch < 4; ++ch) {
        const bool up = (ch < 2) ? UPA : UPB;
        const float* xs = (ch < 2) ? xA : xB;
        const float* cs = (ch < 2) ? cA : cB;
        const int sch = ch & 1;
        const size_t base = up ? ((size_t)sch * NB * npixS + (size_t)b * npixS)
                               : ((size_t)sch * chs + (size_t)b * npix);
        for (int i = tid; i < (TY + 2) * (TX + 2); i += 256) {
            const int ly = i / (TX + 2), lx = i % (TX + 2);
            const int gy = y0 + ly, gx = x0 + lx;
            float cv = 0.f, pv = 0.f;
            if (gy >= 0 && gy < H && gx >= 0 && gx < W) {
                const size_t o = up ? (base + (size_t)(gy >> 1) * Ws2 + (gx >> 1))
                                    : (base + (size_t)gy * W + gx);
                cv = cs[o];
                pv = xs[o] * cv;
            }
            sc[ch][ly][lx] = cv;
            sp[ch][ly][lx] = pv;
        }
    }
    __syncthreads();

    const int gh = blockIdx.y * TY + threadIdx.y;
    const int gw = blockIdx.x * TX + threadIdx.x;
    if (gh < H && gw < W) {
        const size_t off = (size_t)b * npix + (size_t)gh * W + gw;
        float xv[2], cv[2];
#pragma unroll
        for (int o = 0; o < 2; ++o) {
            float ca = 0.f, pa = 0.f;
#pragma unroll
            for (int ci = 0; ci < 4; ++ci)
#pragma unroll
                for (int kh = 0; kh < 3; ++kh)
#pragma unroll
                    for (int kw = 0; kw < 3; ++kw) {
                        const float wv = sw[((o * 4 + ci) * 3 + kh) * 3 + kw];
                        ca += wv * sc[ci][threadIdx.y + kh][threadIdx.x + kw];
                        pa += wv * sp[ci][threadIdx.y + kh][threadIdx.x + kw];
                    }
            xv[o] = pa / (ca + 1e-20f) + sb[o];
            cv[o] = ca * sinv[o];
        }
        if (FUSE) {
            const float w40 = w4[0], w41 = w4[1];
            const float ca4 = w40 * cv[0] + w41 * cv[1];
            const float xo = (w40 * xv[0] * cv[0] + w41 * xv[1] * cv[1]) / (ca4 + 1e-20f) + b4[0];
            const float co = ca4 / (w40 + w41);
            xout[off] = xo;
            cout[off] = co;
        } else {
            xout[off] = xv[0]; xout[chs + off] = xv[1];
            cout[off] = cv[0]; cout[chs + off] = cv[1];
        }
    }
}

extern "C" void kernel_launch(void* const* d_in, const int* in_sizes, int n_in,
                              void* d_out, int out_size, void* d_ws, size_t ws_size,
                              hipStream_t stream) {
    const float* x0  = (const float*)d_in[0];
    const float* c0  = (const float*)d_in[1];
    const float* w1  = (const float*)d_in[2];
    const float* w2  = (const float*)d_in[3];
    const float* w3  = (const float*)d_in[4];
    const float* w4  = (const float*)d_in[5];
    const float* w34 = (const float*)d_in[6];
    const float* w23 = (const float*)d_in[7];
    const float* w12 = (const float*)d_in[8];
    const float* b1  = (const float*)d_in[9];
    const float* b2  = (const float*)d_in[10];
    const float* b3  = (const float*)d_in[11];
    const float* b4  = (const float*)d_in[12];
    const float* b34 = (const float*)d_in[13];
    const float* b23 = (const float*)d_in[14];
    const float* b12 = (const float*)d_in[15];

    float* out = (float*)d_out;   // fp32: xout plane then cout plane

    const int H0 = 512, W0 = 640, H1 = 256, W1 = 320, H2 = 128, W2 = 160, H3 = 64, W3 = 80;
    const size_t n0 = (size_t)NB * H0 * W0;
    const size_t n1 = n0 / 4, n2 = n0 / 16, n3 = n0 / 64;

    float* ws = (float*)d_ws;
    float* FAx = ws;            // x1 (2ch) -- persists to the end
    float* FAc = ws + 2 * n0;   // c1 (2ch)
    float* sub = ws + 4 * n0;   // sub-res arena
    float* HPx = sub;               sub += 2 * n1;
    float* HPc = sub;               sub += 2 * n1;
    float* HAx = sub;               sub += 2 * n1;
    float* HAc = sub;               sub += 2 * n1;
    float* QPx = sub;               sub += 2 * n2;
    float* QPc = sub;               sub += 2 * n2;
    float* QAx = sub;               sub += 2 * n2;
    float* QAc = sub;               sub += 2 * n2;
    float* EPx = sub;               sub += 2 * n3;
    float* EPc = sub;               sub += 2 * n3;
    float* EAx = sub;               sub += 2 * n3;
    float* EAc = sub;               sub += 2 * n3;

    dim3 blk(TX, TY);
    auto gdim = [](int W, int H) { return dim3((W + TX - 1) / TX, (H + TY - 1) / TY, NB); };

    // L1+L2+L3+pool fused: x0,c0 -> FA (x1,c1 full res) + HP (pooled half res)
    enc_full_kernel<<<dim3(W0 / FTW, H0 / FTH, NB), 256, 0, stream>>>(
        x0, c0, w1, b1, w2, b2, w3, b3, FAx, FAc, HPx, HPc, H0, W0);

    // L5: HP -> HA (w2,b2)
    navg5_kernel<2><<<gdim(W1, H1), blk, 0, stream>>>(HPx, HPc, w2, b2, HAx, HAc, H1, W1);
    // L6: HA -> HP (w3,b3)   [HP := x2_ds,c2_ds]
    navg5_kernel<2><<<gdim(W1, H1), blk, 0, stream>>>(HAx, HAc, w3, b3, HPx, HPc, H1, W1);
    // pool -> quarter
    pool_kernel<<<(int)((2 * n2 + 255) / 256), 256, 0, stream>>>(HPx, HPc, QPx, QPc, H2, W2);
    // L8: QP -> QA (w2,b2)   [QA := x3_ds,c3_ds]
    navg5_kernel<2><<<gdim(W2, H2), blk, 0, stream>>>(QPx, QPc, w2, b2, QAx, QAc, H2, W2);
    // pool -> eighth
    pool_kernel<<<(int)((2 * n3 + 255) / 256), 256, 0, stream>>>(QAx, QAc, EPx, EPc, H3, W3);
    // L10: EP -> EA (w2,b2)  [EA := x4_ds,c4_ds]
    navg5_kernel<2><<<gdim(W3, H3), blk, 0, stream>>>(EPx, EPc, w2, b2, EAx, EAc, H3, W3);
    // L12: cat(QA, up2(EA)) -> QP (w34,b34)
    navg3_kernel<false, true, false><<<gdim(W2, H2), blk, 0, stream>>>(
        QAx, QAc, EAx, EAc, w34, b34, nullptr, nullptr, QPx, QPc, H2, W2);
    // L14: cat(HP, up2(QP)) -> HA (w23,b23)
    navg3_kernel<false, true, false><<<gdim(W1, H1), blk, 0, stream>>>(
        HPx, HPc, QPx, QPc, w23, b23, nullptr, nullptr, HAx, HAc, H1, W1);
    // L16 + L17 fused: cat(up2(HA), FA) -> full res, then 1x1 w4, fp32 out
    navg3_kernel<true, false, true><<<gdim(W0, H0), blk, 0, stream>>>(
        HAx, HAc, FAx, FAc, w12, b12, w4, b4, out, out + n0, H0, W0);
}

// Round 8
// 491.776 us; speedup vs baseline: 1.1662x; 1.0422x over previous
//
#include <hip/hip_runtime.h>

// PretrainedCNN: normalized-convolution U-Net, B=16, 512x640, NC=2.
// Inputs fp32; OUTPUT d_out fp32: xout plane (n0) then cout plane (n0).
// Intermediates fp32 planar [ch][b][h][w], plane stride NB*npix.
// Round 8: enc_full conflict fix — float4 inter-stage LDS stores (was scalar
// b32 with 4-dword lane stride = 4-way conflicts, 37% of cycles) + s0/s2
// LDS overlay (36.9 -> 26.9 KB, 4 -> 5 blocks/CU).

#define NB 16

constexpr int TX = 32, TY = 8;

// ================= fused full-res encoder =================
// output tile 32x16; stage 44x28 (halo 6); L1 40x24 (halo 4); L2 36x20 (halo 2)
constexpr int FTW = 32, FTH = 16;
constexpr int FSW = 44, FSH = 28;
constexpr int FAW = 40, FAH = 24;
constexpr int FBW = 36, FBH = 20;

template<int CIN>
__device__ __forceinline__ void conv5x4(const float* sc, const float* sp,
                                        int chStride, int rw,
                                        const float* __restrict__ w,
                                        float ca[2][4], float pa[2][4]) {
#pragma unroll
    for (int o = 0; o < 2; ++o)
#pragma unroll
        for (int j = 0; j < 4; ++j) { ca[o][j] = 0.f; pa[o][j] = 0.f; }
#pragma unroll
    for (int ci = 0; ci < CIN; ++ci) {
#pragma unroll
        for (int kh = 0; kh < 5; ++kh) {
            const float* rc = sc + ci * chStride + kh * rw;
            const float* rp = sp + ci * chStride + kh * rw;
            float cw[8], pw[8];
            *(float4*)&cw[0] = *(const float4*)rc;
            *(float4*)&cw[4] = *(const float4*)(rc + 4);
            *(float4*)&pw[0] = *(const float4*)rp;
            *(float4*)&pw[4] = *(const float4*)(rp + 4);
#pragma unroll
            for (int kw = 0; kw < 5; ++kw) {
                const float w0 = w[(0 * CIN + ci) * 25 + kh * 5 + kw];
                const float w1 = w[(1 * CIN + ci) * 25 + kh * 5 + kw];
#pragma unroll
                for (int j = 0; j < 4; ++j) {
                    ca[0][j] += w0 * cw[j + kw]; pa[0][j] += w0 * pw[j + kw];
                    ca[1][j] += w1 * cw[j + kw]; pa[1][j] += w1 * pw[j + kw];
                }
            }
        }
    }
}

// s0 (input stage) and s2 (L2 output) never live simultaneously: overlay.
union EncSmem {
    struct { float c[FSH][FSW]; float p[FSH][FSW]; } s0;                 // 9856 B
    struct { float c[2][FBH][FBW]; float p[2][FBH][FBW]; } s2;           // 11520 B
};

__global__ __launch_bounds__(256)
void enc_full_kernel(const float* __restrict__ x0, const float* __restrict__ c0,
                     const float* __restrict__ w1, const float* __restrict__ b1,
                     const float* __restrict__ w2, const float* __restrict__ b2,
                     const float* __restrict__ w3, const float* __restrict__ b3,
                     float* __restrict__ FAx, float* __restrict__ FAc,
                     float* __restrict__ HPx, float* __restrict__ HPc,
                     int H, int W) {
    __shared__ __align__(16) EncSmem u;
    __shared__ __align__(16) float s1c[2][FAH][FAW], s1p[2][FAH][FAW];

    const int tid = threadIdx.x;
    const int b = blockIdx.z;
    const int Y0 = blockIdx.y * FTH, X0 = blockIdx.x * FTW;
    const int npix = H * W;
    const size_t bofs = (size_t)b * npix;
    const size_t chs = (size_t)NB * npix;

    auto wsum = [](const float* w, int n) { float s = 0.f; for (int i = 0; i < n; ++i) s += w[i]; return s; };
    const float inv1[2] = {1.f / wsum(w1, 25),  1.f / wsum(w1 + 25, 25)};
    const float inv2[2] = {1.f / wsum(w2, 50),  1.f / wsum(w2 + 50, 50)};
    const float inv3[2] = {1.f / wsum(w3, 50),  1.f / wsum(w3 + 50, 50)};
    const float bb1[2] = {b1[0], b1[1]};
    const float bb2[2] = {b2[0], b2[1]};
    const float bb3[2] = {b3[0], b3[1]};

    // stage input tile (zero-padded outside image)
    for (int i = tid; i < FSH * FSW; i += 256) {
        const int ly = i / FSW, lx = i - ly * FSW;
        const int gy = Y0 + ly - 6, gx = X0 + lx - 6;
        float cv = 0.f, pv = 0.f;
        if (gy >= 0 && gy < H && gx >= 0 && gx < W) {
            const size_t o = bofs + (size_t)gy * W + gx;
            cv = c0[o]; pv = x0[o] * cv;
        }
        u.s0.c[ly][lx] = cv; u.s0.p[ly][lx] = pv;
    }
    __syncthreads();

    // ---- L1: 40x24, CIN=1 -> s1 (float4 stores) ----
    if (tid < FAH * (FAW / 4)) {
        const int row = tid / (FAW / 4), lx = (tid % (FAW / 4)) * 4;
        float ca[2][4], pa[2][4];
        conv5x4<1>(&u.s0.c[row][lx], &u.s0.p[row][lx], 0, FSW, w1, ca, pa);
        const int gy = Y0 + row - 4;
#pragma unroll
        for (int o = 0; o < 2; ++o) {
            float cq[4], pq[4];
#pragma unroll
            for (int j = 0; j < 4; ++j) {
                const int gx = X0 + lx + j - 4;
                const bool in = (gy >= 0 && gy < H && gx >= 0 && gx < W);
                const float cv = in ? ca[o][j] * inv1[o] : 0.f;
                const float xv = pa[o][j] / (ca[o][j] + 1e-20f) + bb1[o];
                cq[j] = cv;
                pq[j] = in ? xv * cv : 0.f;
            }
            *(float4*)&s1c[o][row][lx] = make_float4(cq[0], cq[1], cq[2], cq[3]);
            *(float4*)&s1p[o][row][lx] = make_float4(pq[0], pq[1], pq[2], pq[3]);
        }
    }
    __syncthreads();   // also: s0 reads complete -> s2 may overwrite the union

    // ---- L2: 36x20, CIN=2 -> s2 (float4 stores, overlays s0) ----
    if (tid < FBH * (FBW / 4)) {
        const int row = tid / (FBW / 4), lx = (tid % (FBW / 4)) * 4;
        float ca[2][4], pa[2][4];
        conv5x4<2>(&s1c[0][row][lx], &s1p[0][row][lx], FAH * FAW, FAW, w2, ca, pa);
        const int gy = Y0 + row - 2;
#pragma unroll
        for (int o = 0; o < 2; ++o) {
            float cq[4], pq[4];
#pragma unroll
            for (int j = 0; j < 4; ++j) {
                const int gx = X0 + lx + j - 2;
                const bool in = (gy >= 0 && gy < H && gx >= 0 && gx < W);
                const float cv = in ? ca[o][j] * inv2[o] : 0.f;
                const float xv = pa[o][j] / (ca[o][j] + 1e-20f) + bb2[o];
                cq[j] = cv;
                pq[j] = in ? xv * cv : 0.f;
            }
            *(float4*)&u.s2.c[o][row][lx] = make_float4(cq[0], cq[1], cq[2], cq[3]);
            *(float4*)&u.s2.p[o][row][lx] = make_float4(pq[0], pq[1], pq[2], pq[3]);
        }
    }
    __syncthreads();

    // ---- L3: 32x16, CIN=2 -> global FA + pooled HP ----
    if (tid < FTH * (FTW / 4)) {
        const int row = tid / (FTW / 4), lx = (tid % (FTW / 4)) * 4;
        float ca[2][4], pa[2][4];
        conv5x4<2>(&u.s2.c[0][row][lx], &u.s2.p[0][row][lx], FBH * FBW, FBW, w3, ca, pa);
        float xv[2][4], cv[2][4];
#pragma unroll
        for (int o = 0; o < 2; ++o)
#pragma unroll
            for (int j = 0; j < 4; ++j) {
                xv[o][j] = pa[o][j] / (ca[o][j] + 1e-20f) + bb3[o];
                cv[o][j] = ca[o][j] * inv3[o];
            }
        const int gy = Y0 + row;
        const size_t base = bofs + (size_t)gy * W + (X0 + lx);
#pragma unroll
        for (int o = 0; o < 2; ++o) {
            *(float4*)(FAx + o * chs + base) = make_float4(xv[o][0], xv[o][1], xv[o][2], xv[o][3]);
            *(float4*)(FAc + o * chs + base) = make_float4(cv[o][0], cv[o][1], cv[o][2], cv[o][3]);
        }
        // pool 2x2 (first-wins argmax of c): partner row via shfl_xor(8)
        float pcv[2][4], pxv[2][4];
#pragma unroll
        for (int o = 0; o < 2; ++o)
#pragma unroll
            for (int j = 0; j < 4; ++j) {
                pcv[o][j] = __shfl_xor(cv[o][j], 8);
                pxv[o][j] = __shfl_xor(xv[o][j], 8);
            }
        if ((row & 1) == 0) {
            const int Wh = W >> 1;
            const int np1 = (H >> 1) * Wh;
            const int hy = (Y0 + row) >> 1;
            const int hx0 = (X0 + lx) >> 1;
#pragma unroll
            for (int o = 0; o < 2; ++o)
#pragma unroll
                for (int g = 0; g < 2; ++g) {
                    const float c00 = cv[o][2 * g], c01 = cv[o][2 * g + 1];
                    const float c10 = pcv[o][2 * g], c11 = pcv[o][2 * g + 1];
                    const float x00 = xv[o][2 * g], x01 = xv[o][2 * g + 1];
                    const float x10 = pxv[o][2 * g], x11 = pxv[o][2 * g + 1];
                    float bc = c00, bx = x00;
                    if (c01 > bc) { bc = c01; bx = x01; }
                    if (c10 > bc) { bc = c10; bx = x10; }
                    if (c11 > bc) { bc = c11; bx = x11; }
                    const size_t ho = (size_t)o * NB * np1 + (size_t)b * np1 + (size_t)hy * Wh + hx0 + g;
                    HPc[ho] = bc * 0.25f;
                    HPx[ho] = bx;
                }
        }
    }
}

// ================= original (validated) kernels for sub-res =================
template<int CIN>
__global__ __launch_bounds__(256)
void navg5_kernel(const float* __restrict__ xin, const float* __restrict__ cin,
                  const float* __restrict__ w, const float* __restrict__ bias,
                  float* __restrict__ xout, float* __restrict__ cout,
                  int H, int W) {
    __shared__ float sc[CIN][TY + 4][TX + 4];
    __shared__ float sp[CIN][TY + 4][TX + 4];
    __shared__ float sw[2 * CIN * 25];
    __shared__ float sb[2];
    __shared__ float sinv[2];

    const int b = blockIdx.z;
    const int npix = H * W;
    const size_t chs = (size_t)NB * npix;
    const int tid = threadIdx.y * TX + threadIdx.x;

    for (int i = tid; i < 2 * CIN * 25; i += 256) sw[i] = w[i];
    __syncthreads();
    if (tid < 2) {
        float s = 0.f;
        for (int i = 0; i < CIN * 25; ++i) s += sw[tid * CIN * 25 + i];
        sinv[tid] = 1.f / s;
        sb[tid] = bias[tid];
    }

    const int y0 = blockIdx.y * TY - 2;
    const int x0 = blockIdx.x * TX - 2;
    for (int ci = 0; ci < CIN; ++ci) {
        const size_t base = (size_t)ci * chs + (size_t)b * npix;
        for (int i = tid; i < (TY + 4) * (TX + 4); i += 256) {
            const int ly = i / (TX + 4), lx = i % (TX + 4);
            const int gy = y0 + ly, gx = x0 + lx;
            float cv = 0.f, pv = 0.f;
            if (gy >= 0 && gy < H && gx >= 0 && gx < W) {
                const size_t o = base + (size_t)gy * W + gx;
                cv = cin[o];
                pv = xin[o] * cv;
            }
            sc[ci][ly][lx] = cv;
            sp[ci][ly][lx] = pv;
        }
    }
    __syncthreads();

    const int gh = blockIdx.y * TY + threadIdx.y;
    const int gw = blockIdx.x * TX + threadIdx.x;
    if (gh < H && gw < W) {
        const size_t off = (size_t)b * npix + (size_t)gh * W + gw;
#pragma unroll
        for (int o = 0; o < 2; ++o) {
            float ca = 0.f, pa = 0.f;
#pragma unroll
            for (int ci = 0; ci < CIN; ++ci)
#pragma unroll
                for (int kh = 0; kh < 5; ++kh)
#pragma unroll
                    for (int kw = 0; kw < 5; ++kw) {
                        const float wv = sw[((o * CIN + ci) * 5 + kh) * 5 + kw];
                        ca += wv * sc[ci][threadIdx.y + kh][threadIdx.x + kw];
                        pa += wv * sp[ci][threadIdx.y + kh][threadIdx.x + kw];
                    }
            xout[(size_t)o * chs + off] = pa / (ca + 1e-20f) + sb[o];
            cout[(size_t)o * chs + off] = ca * sinv[o];
        }
    }
}

__global__ void pool_kernel(const float* __restrict__ xin, const float* __restrict__ cin,
                            float* __restrict__ xout, float* __restrict__ cout,
                            int Hh, int Wh) {
    const int nplane = Hh * Wh;
    const int total = 2 * NB * nplane;
    const int idx = blockIdx.x * blockDim.x + threadIdx.x;
    if (idx >= total) return;
    const int p = idx / nplane;
    const int q = idx - p * nplane;
    const int h = q / Wh, wc = q - h * Wh;
    const int Wf = 2 * Wh;
    const size_t ibase = (size_t)p * 4 * nplane + (size_t)(2 * h) * Wf + 2 * wc;
    const float c00 = cin[ibase], c01 = cin[ibase + 1];
    const float c10 = cin[ibase + Wf], c11 = cin[ibase + Wf + 1];
    float best = c00; size_t boff = ibase;
    if (c01 > best) { best = c01; boff = ibase + 1; }
    if (c10 > best) { best = c10; boff = ibase + Wf; }
    if (c11 > best) { best = c11; boff = ibase + Wf + 1; }
    cout[idx] = best * 0.25f;
    xout[idx] = xin[boff];
}

template<bool UPA, bool UPB, bool FUSE>
__global__ __launch_bounds__(256)
void navg3_kernel(const float* __restrict__ xA, const float* __restrict__ cA,
                  const float* __restrict__ xB, const float* __restrict__ cB,
                  const float* __restrict__ w, const float* __restrict__ bias,
                  const float* __restrict__ w4, const float* __restrict__ b4,
                  float* __restrict__ xout, float* __restrict__ cout,
                  int H, int W) {
    __shared__ float sc[4][TY + 2][TX + 2];
    __shared__ float sp[4][TY + 2][TX + 2];
    __shared__ float sw[72];
    __shared__ float sb[2];
    __shared__ float sinv[2];

    const int b = blockIdx.z;
    const int npix = H * W;
    const size_t chs = (size_t)NB * npix;
    const int tid = threadIdx.y * TX + threadIdx.x;

    if (tid < 72) sw[tid] = w[tid];
    __syncthreads();
    if (tid < 2) {
        float s = 0.f;
        for (int i = 0; i < 36; ++i) s += sw[tid * 36 + i];
        sinv[tid] = 1.f / s;
        sb[tid] = bias[tid];
    }

    const int y0 = blockIdx.y * TY - 1;
    const int x0 = blockIdx.x * TX - 1;
    const int Ws2 = W >> 1;
    const int npixS = (H >> 1) * Ws2;

#pragma unroll
    for (int ch = 0; ch < 4; ++ch) {
        const bool up = (ch < 2) ? UPA : UPB;
        const float* xs = (ch < 2) ? xA : xB;
        const float* cs = (ch < 2) ? cA : cB;
        const int sch = ch & 1;
        const size_t base = up ? ((size_t)sch * NB * npixS + (size_t)b * npixS)
                               : ((size_t)sch * chs + (size_t)b * npix);
        for (int i = tid; i < (TY + 2) * (TX + 2); i += 256) {
            const int ly = i / (TX + 2), lx = i % (TX + 2);
            const int gy = y0 + ly, gx = x0 + lx;
            float cv = 0.f, pv = 0.f;
            if (gy >= 0 && gy < H && gx >= 0 && gx < W) {
                const size_t o = up ? (base + (size_t)(gy >> 1) * Ws2 + (gx >> 1))
                                    : (base + (size_t)gy * W + gx);
                cv = cs[o];
                pv = xs[o] * cv;
            }
            sc[ch][ly][lx] = cv;
            sp[ch][ly][lx] = pv;
        }
    }
    __syncthreads();

    const int gh = blockIdx.y * TY + threadIdx.y;
    const int gw = blockIdx.x * TX + threadIdx.x;
    if (gh < H && gw < W) {
        const size_t off = (size_t)b * npix + (size_t)gh * W + gw;
        float xv[2], cv[2];
#pragma unroll
        for (int o = 0; o < 2; ++o) {
            float ca = 0.f, pa = 0.f;
#pragma unroll
            for (int ci = 0; ci < 4; ++ci)
#pragma unroll
                for (int kh = 0; kh < 3; ++kh)
#pragma unroll
                    for (int kw = 0; kw < 3; ++kw) {
                        const float wv = sw[((o * 4 + ci) * 3 + kh) * 3 + kw];
                        ca += wv * sc[ci][threadIdx.y + kh][threadIdx.x + kw];
                        pa += wv * sp[ci][threadIdx.y + kh][threadIdx.x + kw];
                    }
            xv[o] = pa / (ca + 1e-20f) + sb[o];
            cv[o] = ca * sinv[o];
        }
        if (FUSE) {
            const float w40 = w4[0], w41 = w4[1];
            const float ca4 = w40 * cv[0] + w41 * cv[1];
            const float xo = (w40 * xv[0] * cv[0] + w41 * xv[1] * cv[1]) / (ca4 + 1e-20f) + b4[0];
            const float co = ca4 / (w40 + w41);
            xout[off] = xo;
            cout[off] = co;
        } else {
            xout[off] = xv[0]; xout[chs + off] = xv[1];
            cout[off] = cv[0]; cout[chs + off] = cv[1];
        }
    }
}

extern "C" void kernel_launch(void* const* d_in, const int* in_sizes, int n_in,
                              void* d_out, int out_size, void* d_ws, size_t ws_size,
                              hipStream_t stream) {
    const float* x0  = (const float*)d_in[0];
    const float* c0  = (const float*)d_in[1];
    const float* w1  = (const float*)d_in[2];
    const float* w2  = (const float*)d_in[3];
    const float* w3  = (const float*)d_in[4];
    const float* w4  = (const float*)d_in[5];
    const float* w34 = (const float*)d_in[6];
    const float* w23 = (const float*)d_in[7];
    const float* w12 = (const float*)d_in[8];
    const float* b1  = (const float*)d_in[9];
    const float* b2  = (const float*)d_in[10];
    const float* b3  = (const float*)d_in[11];
    const float* b4  = (const float*)d_in[12];
    const float* b34 = (const float*)d_in[13];
    const float* b23 = (const float*)d_in[14];
    const float* b12 = (const float*)d_in[15];

    float* out = (float*)d_out;   // fp32: xout plane then cout plane

    const int H0 = 512, W0 = 640, H1 = 256, W1 = 320, H2 = 128, W2 = 160, H3 = 64, W3 = 80;
    const size_t n0 = (size_t)NB * H0 * W0;
    const size_t n1 = n0 / 4, n2 = n0 / 16, n3 = n0 / 64;

    float* ws = (float*)d_ws;
    float* FAx = ws;            // x1 (2ch) -- persists to the end
    float* FAc = ws + 2 * n0;   // c1 (2ch)
    float* sub = ws + 4 * n0;   // sub-res arena
    float* HPx = sub;               sub += 2 * n1;
    float* HPc = sub;               sub += 2 * n1;
    float* HAx = sub;               sub += 2 * n1;
    float* HAc = sub;               sub += 2 * n1;
    float* QPx = sub;               sub += 2 * n2;
    float* QPc = sub;               sub += 2 * n2;
    float* QAx = sub;               sub += 2 * n2;
    float* QAc = sub;               sub += 2 * n2;
    float* EPx = sub;               sub += 2 * n3;
    float* EPc = sub;               sub += 2 * n3;
    float* EAx = sub;               sub += 2 * n3;
    float* EAc = sub;               sub += 2 * n3;

    dim3 blk(TX, TY);
    auto gdim = [](int W, int H) { return dim3((W + TX - 1) / TX, (H + TY - 1) / TY, NB); };

    // L1+L2+L3+pool fused: x0,c0 -> FA (x1,c1 full res) + HP (pooled half res)
    enc_full_kernel<<<dim3(W0 / FTW, H0 / FTH, NB), 256, 0, stream>>>(
        x0, c0, w1, b1, w2, b2, w3, b3, FAx, FAc, HPx, HPc, H0, W0);

    // L5: HP -> HA (w2,b2)
    navg5_kernel<2><<<gdim(W1, H1), blk, 0, stream>>>(HPx, HPc, w2, b2, HAx, HAc, H1, W1);
    // L6: HA -> HP (w3,b3)   [HP := x2_ds,c2_ds]
    navg5_kernel<2><<<gdim(W1, H1), blk, 0, stream>>>(HAx, HAc, w3, b3, HPx, HPc, H1, W1);
    // pool -> quarter
    pool_kernel<<<(int)((2 * n2 + 255) / 256), 256, 0, stream>>>(HPx, HPc, QPx, QPc, H2, W2);
    // L8: QP -> QA (w2,b2)   [QA := x3_ds,c3_ds]
    navg5_kernel<2><<<gdim(W2, H2), blk, 0, stream>>>(QPx, QPc, w2, b2, QAx, QAc, H2, W2);
    // pool -> eighth
    pool_kernel<<<(int)((2 * n3 + 255) / 256), 256, 0, stream>>>(QAx, QAc, EPx, EPc, H3, W3);
    // L10: EP -> EA (w2,b2)  [EA := x4_ds,c4_ds]
    navg5_kernel<2><<<gdim(W3, H3), blk, 0, stream>>>(EPx, EPc, w2, b2, EAx, EAc, H3, W3);
    // L12: cat(QA, up2(EA)) -> QP (w34,b34)
    navg3_kernel<false, true, false><<<gdim(W2, H2), blk, 0, stream>>>(
        QAx, QAc, EAx, EAc, w34, b34, nullptr, nullptr, QPx, QPc, H2, W2);
    // L14: cat(HP, up2(QP)) -> HA (w23,b23)
    navg3_kernel<false, true, false><<<gdim(W1, H1), blk, 0, stream>>>(
        HPx, HPc, QPx, QPc, w23, b23, nullptr, nullptr, HAx, HAc, H1, W1);
    // L16 + L17 fused: cat(up2(HA), FA) -> full res, then 1x1 w4, fp32 out
    navg3_kernel<true, false, true><<<gdim(W0, H0), blk, 0, stream>>>(
        HAx, HAc, FAx, FAc, w12, b12, w4, b4, out, out + n0, H0, W0);
}